// Round 1
// baseline (368.463 us; speedup 1.0000x reference)
//
#include <hip/hip_runtime.h>

// Tensor Fusion Network, MI355X.
// Stage 1 (k1): fusion[b][p] (bf16), p=(i*49+j)*97+k, via MFMA: w[ij,t] @ x[t,k] per b.
// Stage 2 (k2): split-K GEMM h1-partials = fusion[128 x 232897] @ W1 (bf16 MFMA).
// Stage 3 (k3): reduce partials + bias + relu -> h1.
// Stage 4 (k4,k5): tiny MLP tail in fp32 vector.

#define B_    128
#define T_    64
#define A1    49
#define V1    49
#define X1    97
#define IJ    2401      // 49*49
#define KTOT  232897    // IJ*97
#define FP    232928    // KTOT padded up to multiple of 32
#define PF    128
#define KC    512       // K-chunk per k2 block
#define NB2   455       // ceil(KTOT/KC)

typedef short s8v __attribute__((ext_vector_type(8)));   // 8 bf16 (4 VGPRs)
typedef float f4v __attribute__((ext_vector_type(4)));   // 4 fp32 acc

__device__ __forceinline__ unsigned short f2bf(float f) {
    union { float f; unsigned u; } v; v.f = f;
    return (unsigned short)((v.u + 0x7FFFu + ((v.u >> 16) & 1u)) >> 16); // RNE
}

// ---------------- k1: fusion (bf16) -------------------------------------
// grid (10, 128): blockIdx.y = b, blockIdx.x covers 256 ij (4 chunks of 64).
// Per chunk: w_s[64 ij][64 t] = a*v in LDS (bf16); MFMA [16ij x 16k] tiles,
// K = t = 64 (2 x mfma_16x16x32).
__global__ __launch_bounds__(256) void k1_fusion(
    const float* __restrict__ audio, const float* __restrict__ video,
    const float* __restrict__ text, unsigned short* __restrict__ fusion)
{
    __shared__ float a_s[T_ * A1];             // [t][i]
    __shared__ float v_s[T_ * V1];             // [t][j]
    __shared__ unsigned short xT[112 * 88];    // [k][t], rows padded to 88 (176B, 16B-mult)
    __shared__ unsigned short w_s[64 * 88];    // [ij_local][t]

    const int b = blockIdx.y;
    const int tid = threadIdx.x;

    for (int idx = tid; idx < T_ * A1; idx += 256) {
        int t = idx / A1, i = idx - t * A1;
        a_s[idx] = (i == 0) ? 1.0f : audio[(b * T_ + t) * 48 + (i - 1)];
    }
    for (int idx = tid; idx < T_ * V1; idx += 256) {
        int t = idx / V1, j = idx - t * V1;
        v_s[idx] = (j == 0) ? 1.0f : video[(b * T_ + t) * 48 + (j - 1)];
    }
    for (int idx = tid; idx < T_ * X1; idx += 256) {
        int t = idx / X1, k = idx - t * X1;
        float val = (k == 0) ? 1.0f : text[(b * T_ + t) * 96 + (k - 1)];
        xT[k * 88 + t] = f2bf(val);
    }
    for (int idx = tid; idx < 15 * 64; idx += 256) {  // zero k = 97..111 (n-tile pad)
        xT[(97 + (idx >> 6)) * 88 + (idx & 63)] = 0;
    }
    __syncthreads();

    const int wave = tid >> 6, lane = tid & 63;
    const int q = lane >> 4, ln = lane & 15;

    for (int c4 = 0; c4 < 4; ++c4) {
        const int ij_base = blockIdx.x * 256 + c4 * 64;
        if (ij_base >= IJ) break;              // block-uniform

        for (int idx = tid; idx < 4096; idx += 256) {
            int ijl = idx >> 6, t = idx & 63;
            int ij = ij_base + ijl;
            unsigned short wv = 0;
            if (ij < IJ) {
                int i = ij / 49, j = ij - i * 49;
                wv = f2bf(a_s[t * A1 + i] * v_s[t * V1 + j]);
            }
            w_s[ijl * 88 + t] = wv;
        }
        __syncthreads();

        // A-frag: lane holds A[m = ln][k(t) = q*8 + 0..7 (+32*kstep)]
        s8v af0 = *(const s8v*)&w_s[(wave * 16 + ln) * 88 + 0 + q * 8];
        s8v af1 = *(const s8v*)&w_s[(wave * 16 + ln) * 88 + 32 + q * 8];
        for (int nt = 0; nt < 7; ++nt) {
            s8v bf0 = *(const s8v*)&xT[(nt * 16 + ln) * 88 + 0 + q * 8];
            s8v bf1 = *(const s8v*)&xT[(nt * 16 + ln) * 88 + 32 + q * 8];
            f4v acc = {0.f, 0.f, 0.f, 0.f};
            acc = __builtin_amdgcn_mfma_f32_16x16x32_bf16(af0, bf0, acc, 0, 0, 0);
            acc = __builtin_amdgcn_mfma_f32_16x16x32_bf16(af1, bf1, acc, 0, 0, 0);
            // C/D: col = ln (k), row = q*4 + r (ij within tile)
            int kk = nt * 16 + ln;
            if (kk < X1) {
                for (int r = 0; r < 4; ++r) {
                    int ij = ij_base + wave * 16 + q * 4 + r;
                    if (ij < IJ)
                        fusion[(size_t)b * FP + ij * X1 + kk] = f2bf(acc[r]);
                }
            }
        }
        __syncthreads();
    }
}

// ---------------- k2: split-K GEMM h1-partials --------------------------
// C[128 b, 128 f] partial = fusion[:, kbase:kbase+KC] @ W1[kbase:kbase+KC, :]
__global__ __launch_bounds__(256) void k2_gemm(
    const unsigned short* __restrict__ fusion, const float* __restrict__ W1,
    float* __restrict__ partials)
{
    __shared__ unsigned short A_l[128 * 56];   // [b][p_local], rows padded to 56 (112B)
    __shared__ unsigned short B_l[128 * 56];   // [f][p_local] (W1 transposed, bf16)

    const int blk = blockIdx.x;
    const int kbase = blk * KC;
    const int nsteps = min(KC >> 5, (FP - kbase) >> 5);
    const int tid = threadIdx.x;
    const int wave = tid >> 6, lane = tid & 63;
    const int q = lane >> 4, ln = lane & 15;

    f4v acc[2][8];
    for (int h = 0; h < 2; ++h)
        for (int n = 0; n < 8; ++n) acc[h][n] = (f4v){0.f, 0.f, 0.f, 0.f};

    for (int s = 0; s < nsteps; ++s) {
        const int p0 = kbase + s * 32;
        // stage A: 128 rows x 32 bf16 (pad region of fusion is garbage but B=0 there)
        {
            int m = tid >> 2;            // 0..63
            int kq = (tid & 3) << 3;     // 0,8,16,24
            *(uint4*)&A_l[m * 56 + kq] =
                *(const uint4*)&fusion[(size_t)m * FP + p0 + kq];
            *(uint4*)&A_l[(m + 64) * 56 + kq] =
                *(const uint4*)&fusion[(size_t)(m + 64) * FP + p0 + kq];
        }
        // stage B^T: W1[p0+pl][f] fp32 -> bf16 -> B_l[f][pl]
        {
            int pl = tid >> 5;           // 0..7
            int f4i = (tid & 31) << 2;   // 0..124
            for (int qq = 0; qq < 4; ++qq) {
                int p = p0 + pl + qq * 8;
                float4 v = make_float4(0.f, 0.f, 0.f, 0.f);
                if (p < KTOT) v = *(const float4*)&W1[(size_t)p * PF + f4i];
                B_l[(f4i + 0) * 56 + pl + qq * 8] = f2bf(v.x);
                B_l[(f4i + 1) * 56 + pl + qq * 8] = f2bf(v.y);
                B_l[(f4i + 2) * 56 + pl + qq * 8] = f2bf(v.z);
                B_l[(f4i + 3) * 56 + pl + qq * 8] = f2bf(v.w);
            }
        }
        __syncthreads();
        s8v a0 = *(const s8v*)&A_l[((wave * 2 + 0) * 16 + ln) * 56 + q * 8];
        s8v a1 = *(const s8v*)&A_l[((wave * 2 + 1) * 16 + ln) * 56 + q * 8];
        #pragma unroll
        for (int nt = 0; nt < 8; ++nt) {
            s8v bf = *(const s8v*)&B_l[(nt * 16 + ln) * 56 + q * 8];
            acc[0][nt] = __builtin_amdgcn_mfma_f32_16x16x32_bf16(a0, bf, acc[0][nt], 0, 0, 0);
            acc[1][nt] = __builtin_amdgcn_mfma_f32_16x16x32_bf16(a1, bf, acc[1][nt], 0, 0, 0);
        }
        __syncthreads();
    }

    float* outp = partials + (size_t)blk * (128 * 128);
    for (int h = 0; h < 2; ++h) {
        int mrow = (wave * 2 + h) * 16 + q * 4;
        for (int nt = 0; nt < 8; ++nt) {
            int f = nt * 16 + ln;
            for (int r = 0; r < 4; ++r)
                outp[(mrow + r) * 128 + f] = acc[h][nt][r];
        }
    }
}

// ---------------- k3: reduce partials + bias + relu ---------------------
__global__ __launch_bounds__(256) void k3_reduce(
    const float* __restrict__ partials, const float* __restrict__ b1,
    float* __restrict__ h1)
{
    int e = blockIdx.x * 256 + threadIdx.x;   // e = b*128 + f, 16384 total
    float s = 0.f;
    for (int r = 0; r < NB2; ++r) s += partials[(size_t)r * 16384 + e];
    s += b1[e & 127];
    h1[e] = fmaxf(s, 0.f);
}

// ---------------- k4: h2 = relu(h1 @ W2 + b2) ---------------------------
__global__ __launch_bounds__(256) void k4_mlp(
    const float* __restrict__ h1, const float* __restrict__ W2,
    const float* __restrict__ b2, float* __restrict__ h2)
{
    int idx = blockIdx.x * 256 + threadIdx.x;
    int b = idx >> 7, f = idx & 127;
    float s = b2[f];
    for (int c = 0; c < 128; ++c) s += h1[b * 128 + c] * W2[c * 128 + f];
    h2[idx] = fmaxf(s, 0.f);
}

// ---------------- k5: out = sigmoid(h2 @ W3 + b3)*6 - 3 -----------------
__global__ __launch_bounds__(128) void k5_out(
    const float* __restrict__ h2, const float* __restrict__ W3,
    const float* __restrict__ b3, float* __restrict__ out)
{
    int b = threadIdx.x;
    float s = b3[0];
    for (int c = 0; c < 128; ++c) s += h2[b * 128 + c] * W3[c];
    out[b] = 6.0f / (1.0f + expf(-s)) - 3.0f;
}

extern "C" void kernel_launch(void* const* d_in, const int* in_sizes, int n_in,
                              void* d_out, int out_size, void* d_ws, size_t ws_size,
                              hipStream_t stream)
{
    const float* audio = (const float*)d_in[0];
    const float* video = (const float*)d_in[1];
    const float* text  = (const float*)d_in[2];
    const float* W1 = (const float*)d_in[3];
    const float* b1 = (const float*)d_in[4];
    const float* W2 = (const float*)d_in[5];
    const float* b2 = (const float*)d_in[6];
    const float* W3 = (const float*)d_in[7];
    const float* b3 = (const float*)d_in[8];
    float* out = (float*)d_out;

    // ws layout (bytes): fusion bf16 [128][232928] = 59,629,568
    //                    partials fp32 [455][16384] = 29,818,880 @ 59,629,568
    //                    h1 [16384] fp32 @ 89,448,448 ; h2 @ 89,513,984
    //                    total used: 89,579,520
    char* ws = (char*)d_ws;
    unsigned short* fusion = (unsigned short*)ws;
    float* partials = (float*)(ws + 59629568);
    float* h1 = (float*)(ws + 89448448);
    float* h2 = (float*)(ws + 89513984);

    k1_fusion<<<dim3(10, 128), 256, 0, stream>>>(audio, video, text, fusion);
    k2_gemm<<<dim3(NB2), 256, 0, stream>>>(fusion, W1, partials);
    k3_reduce<<<dim3(64), 256, 0, stream>>>(partials, b1, h1);
    k4_mlp<<<dim3(64), 256, 0, stream>>>(h1, W2, b2, h2);
    k5_out<<<dim3(1), 128, 0, stream>>>(h2, W3, b3, out);
}

// Round 2
// 277.515 us; speedup vs baseline: 1.3277x; 1.3277x over previous
//
#include <hip/hip_runtime.h>

// Tensor Fusion Network, MI355X. Round 2.
// k1: fusion[b][p] bf16 (p = ij*97+k) via per-wave MFMA, barrier-free main loop.
// k2: split-K GEMM h1-partials = fusion[128 x K] @ bf16(W1), vectorized staging.
// k3: parallel reduce + bias + relu. k4/k5: MLP tail.

#define B_    128
#define T_    64
#define A1    49
#define V1    49
#define X1    97
#define IJ    2401      // 49*49
#define KTOT  232897    // IJ*97
#define FP    232928    // KTOT padded to multiple of 32
#define PF    128
#define KC    512
#define NB2   455       // ceil(FP/KC)

typedef short s8v __attribute__((ext_vector_type(8)));   // 8 bf16
typedef float f4v __attribute__((ext_vector_type(4)));   // 4 fp32

__device__ __forceinline__ unsigned short f2bf(float f) {
    union { float f; unsigned u; } v; v.f = f;
    return (unsigned short)((v.u + 0x7FFFu + ((v.u >> 16) & 1u)) >> 16); // RNE
}

// ---------------- k1: fusion (bf16) -------------------------------------
// grid (4, 128): blockIdx.y = b, blockIdx.x covers 38 ij-tiles of 16 (151 total).
// 512 threads = 8 waves; each wave owns a private w-slice in LDS -> no barriers
// after initial staging.
__global__ __launch_bounds__(512) void k1_fusion(
    const float* __restrict__ audio, const float* __restrict__ video,
    const float* __restrict__ text, unsigned short* __restrict__ fusion)
{
    __shared__ float a_s[T_ * A1];                 // [t][i]
    __shared__ float v_s[T_ * V1];                 // [t][j]
    __shared__ unsigned short xT[112 * 72];        // [k][t], rows padded to 72
    __shared__ unsigned short w_ws[8][16 * 72];    // per-wave [ij_local][t]

    const int b = blockIdx.y;
    const int bx = blockIdx.x;
    const int tid = threadIdx.x;

    for (int idx = tid; idx < T_ * A1; idx += 512) {
        int t = idx / 49, i = idx - t * 49;
        a_s[idx] = (i == 0) ? 1.0f : audio[(b * T_ + t) * 48 + (i - 1)];
        v_s[idx] = (i == 0) ? 1.0f : video[(b * T_ + t) * 48 + (i - 1)];
    }
    for (int idx = tid; idx < T_ * X1; idx += 512) {
        int t = idx / 97, k = idx - t * 97;
        xT[k * 72 + t] = f2bf((k == 0) ? 1.0f : text[(b * T_ + t) * 96 + (k - 1)]);
    }
    for (int idx = tid; idx < 15 * 64; idx += 512) {   // zero pad rows k=97..111
        xT[(97 + (idx >> 6)) * 72 + (idx & 63)] = 0;
    }
    __syncthreads();

    const int wave = tid >> 6, lane = tid & 63;
    const int q = lane >> 4, ln = lane & 15;
    unsigned short* w_s = w_ws[wave];

    for (int it = 0; it < 5; ++it) {
        const int tw = it * 8 + wave;          // tile-within-x-block
        if (tw >= 38) break;                   // wave-uniform
        const int tl = bx * 38 + tw;           // global 16-ij tile
        if (tl >= 151) break;
        const int ij0 = tl * 16;

        // w-compute: lane = t, loop over 16 local ij (ij wave-uniform per iter)
        #pragma unroll
        for (int ijl = 0; ijl < 16; ++ijl) {
            int ij = ij0 + ijl;
            unsigned short wv = 0;
            if (ij < IJ) {
                int i = ij / 49, j = ij - i * 49;
                wv = f2bf(a_s[lane * 49 + i] * v_s[lane * 49 + j]);
            }
            w_s[ijl * 72 + lane] = wv;
        }
        // A-frags: lane holds A[m=ln][t = q*8 + 0..7 (+32)]
        s8v af0 = *(const s8v*)&w_s[ln * 72 + q * 8];
        s8v af1 = *(const s8v*)&w_s[ln * 72 + 32 + q * 8];
        #pragma unroll
        for (int nt = 0; nt < 7; ++nt) {
            s8v bf0 = *(const s8v*)&xT[(nt * 16 + ln) * 72 + q * 8];
            s8v bf1 = *(const s8v*)&xT[(nt * 16 + ln) * 72 + 32 + q * 8];
            f4v acc = {0.f, 0.f, 0.f, 0.f};
            acc = __builtin_amdgcn_mfma_f32_16x16x32_bf16(af0, bf0, acc, 0, 0, 0);
            acc = __builtin_amdgcn_mfma_f32_16x16x32_bf16(af1, bf1, acc, 0, 0, 0);
            int kk = nt * 16 + ln;             // C: col=ln -> k, row=q*4+r -> ij
            if (kk < X1) {
                #pragma unroll
                for (int r = 0; r < 4; ++r) {
                    int ij = ij0 + q * 4 + r;
                    if (ij < IJ)
                        fusion[(size_t)b * FP + ij * X1 + kk] = f2bf(acc[r]);
                }
            }
        }
    }
}

// ---------------- k2: split-K GEMM h1-partials --------------------------
__global__ __launch_bounds__(256) void k2_gemm(
    const unsigned short* __restrict__ fusion, const float* __restrict__ W1,
    float* __restrict__ partials)
{
    __shared__ unsigned short A_l[128 * 40];   // [b][p_local], rows padded to 40
    __shared__ unsigned short B_l[128 * 40];   // [f][p_local]

    const int blk = blockIdx.x;
    const int kbase = blk * KC;
    const int nsteps = min(KC >> 5, (FP - kbase) >> 5);
    const int tid = threadIdx.x;
    const int wave = tid >> 6, lane = tid & 63;
    const int q = lane >> 4, ln = lane & 15;

    const int mA = tid >> 1, halfA = tid & 1;  // A-stage: 32 B per thread
    const int fB = tid & 127, gB = tid >> 7;   // B-stage: 16 p per thread

    f4v acc[2][8];
    for (int h = 0; h < 2; ++h)
        for (int n = 0; n < 8; ++n) acc[h][n] = (f4v){0.f, 0.f, 0.f, 0.f};

    for (int s = 0; s < nsteps; ++s) {
        const int p0 = kbase + s * 32;
        // issue global loads first (overlap previous step's MFMAs)
        uint4 av0 = *(const uint4*)&fusion[(size_t)mA * FP + p0 + halfA * 16];
        uint4 av1 = *(const uint4*)&fusion[(size_t)mA * FP + p0 + halfA * 16 + 8];
        float bv[16];
        #pragma unroll
        for (int c = 0; c < 16; ++c) {
            int p = p0 + gB * 16 + c;          // p-consecutive, lanes span f -> coalesced
            bv[c] = (p < KTOT) ? W1[(size_t)p * PF + fB] : 0.f;
        }
        __syncthreads();                        // prev step's frag reads done
        *(uint4*)&A_l[mA * 40 + halfA * 16] = av0;
        *(uint4*)&A_l[mA * 40 + halfA * 16 + 8] = av1;
        #pragma unroll
        for (int c = 0; c < 4; ++c) {
            ushort4 pk;
            pk.x = f2bf(bv[c * 4 + 0]); pk.y = f2bf(bv[c * 4 + 1]);
            pk.z = f2bf(bv[c * 4 + 2]); pk.w = f2bf(bv[c * 4 + 3]);
            *(ushort4*)&B_l[fB * 40 + gB * 16 + c * 4] = pk;   // 8 B vector write
        }
        __syncthreads();
        s8v a0 = *(const s8v*)&A_l[(wave * 32 + ln) * 40 + q * 8];
        s8v a1 = *(const s8v*)&A_l[(wave * 32 + 16 + ln) * 40 + q * 8];
        #pragma unroll
        for (int nt = 0; nt < 8; ++nt) {
            s8v bf = *(const s8v*)&B_l[(nt * 16 + ln) * 40 + q * 8];
            acc[0][nt] = __builtin_amdgcn_mfma_f32_16x16x32_bf16(a0, bf, acc[0][nt], 0, 0, 0);
            acc[1][nt] = __builtin_amdgcn_mfma_f32_16x16x32_bf16(a1, bf, acc[1][nt], 0, 0, 0);
        }
    }

    float* outp = partials + (size_t)blk * (128 * 128);
    for (int h = 0; h < 2; ++h) {
        int mrow = wave * 32 + h * 16 + q * 4;
        for (int nt = 0; nt < 8; ++nt) {
            int f = nt * 16 + ln;
            for (int r = 0; r < 4; ++r)
                outp[(mrow + r) * 128 + f] = acc[h][nt][r];
        }
    }
}

// ---------------- k3: reduce partials + bias + relu ---------------------
// grid 256 blocks x 256 thr: block owns 64 e-values, 4-way r-split per e.
__global__ __launch_bounds__(256) void k3_reduce(
    const float* __restrict__ partials, const float* __restrict__ b1,
    float* __restrict__ h1)
{
    __shared__ float red[256];
    const int e = blockIdx.x * 64 + (threadIdx.x & 63);
    const int rh = threadIdx.x >> 6;           // 0..3
    float s = 0.f;
    for (int r = rh; r < NB2; r += 4)
        s += partials[(size_t)r * 16384 + e];
    red[threadIdx.x] = s;
    __syncthreads();
    if (threadIdx.x < 64) {
        float v = red[threadIdx.x] + red[threadIdx.x + 64] +
                  red[threadIdx.x + 128] + red[threadIdx.x + 192];
        v += b1[e & 127];
        h1[e] = fmaxf(v, 0.f);
    }
}

// ---------------- k4: h2 = relu(h1 @ W2 + b2) ---------------------------
__global__ __launch_bounds__(128) void k4_mlp(
    const float* __restrict__ h1, const float* __restrict__ W2,
    const float* __restrict__ b2, float* __restrict__ h2)
{
    __shared__ float hrow[128];
    const int b = blockIdx.x, f = threadIdx.x;
    hrow[f] = h1[b * 128 + f];
    __syncthreads();
    float s = b2[f];
    #pragma unroll 8
    for (int c = 0; c < 128; ++c) s += hrow[c] * W2[c * 128 + f];
    h2[b * 128 + f] = fmaxf(s, 0.f);
}

// ---------------- k5: out = sigmoid(h2 @ W3 + b3)*6 - 3 -----------------
__global__ __launch_bounds__(128) void k5_out(
    const float* __restrict__ h2, const float* __restrict__ W3,
    const float* __restrict__ b3, float* __restrict__ out)
{
    int b = threadIdx.x;
    float s = b3[0];
    for (int c = 0; c < 128; ++c) s += h2[b * 128 + c] * W3[c];
    out[b] = 6.0f / (1.0f + expf(-s)) - 3.0f;
}

extern "C" void kernel_launch(void* const* d_in, const int* in_sizes, int n_in,
                              void* d_out, int out_size, void* d_ws, size_t ws_size,
                              hipStream_t stream)
{
    const float* audio = (const float*)d_in[0];
    const float* video = (const float*)d_in[1];
    const float* text  = (const float*)d_in[2];
    const float* W1 = (const float*)d_in[3];
    const float* b1 = (const float*)d_in[4];
    const float* W2 = (const float*)d_in[5];
    const float* b2 = (const float*)d_in[6];
    const float* W3 = (const float*)d_in[7];
    const float* b3 = (const float*)d_in[8];
    float* out = (float*)d_out;

    // ws layout: fusion bf16 [128][FP] = 59,629,568 B
    //            partials fp32 [455][16384] = 29,818,880 B @ 59,629,568
    //            h1 @ 89,448,448 ; h2 @ 89,513,984 ; total 89,579,520 B
    char* ws = (char*)d_ws;
    unsigned short* fusion = (unsigned short*)ws;
    float* partials = (float*)(ws + 59629568);
    float* h1 = (float*)(ws + 89448448);
    float* h2 = (float*)(ws + 89513984);

    k1_fusion<<<dim3(4, 128), 512, 0, stream>>>(audio, video, text, fusion);
    k2_gemm<<<dim3(NB2), 256, 0, stream>>>(fusion, W1, partials);
    k3_reduce<<<dim3(256), 256, 0, stream>>>(partials, b1, h1);
    k4_mlp<<<dim3(128), 128, 0, stream>>>(h1, W2, b2, h2);
    k5_out<<<dim3(1), 128, 0, stream>>>(h2, W3, b3, out);
}